// Round 1
// baseline (2805.478 us; speedup 1.0000x reference)
//
#include <hip/hip_runtime.h>

#define NB 32
#define NC 32
#define NNODE 512
#define NT 168
#define NTO 156
#define NQ 39          // NTO / 4
#define NEMB 40
#define KNEI 20
#define NADJ 21        // 20 neighbors + diagonal

static_assert(NTO == 4 * NQ, "t quads");

// ---------------------------------------------------------------- helpers
__device__ __forceinline__ float fast_tanh(float x) {
  float e = __expf(2.0f * x);
  return 1.0f - 2.0f / (e + 1.0f);
}
__device__ __forceinline__ float fast_sigmoid(float x) {
  return 1.0f / (1.0f + __expf(-x));
}

// ---------------------------------------------------------------- G1: node embeddings
__global__ __launch_bounds__(128) void g1_kernel(
    const float* __restrict__ emb1, const float* __restrict__ emb2,
    const float* __restrict__ W1, const float* __restrict__ b1,
    const float* __restrict__ W2, const float* __restrict__ b2,
    const int* __restrict__ idx, float* __restrict__ n1, float* __restrict__ n2) {
  const int v = blockIdx.x;
  const int tid = threadIdx.x;
  const int iv = idx[v];
  if (tid < NEMB) {
    float s = b1[tid];
    const float* er = emb1 + iv * NEMB;
    const float* wr = W1 + tid * NEMB;
    for (int f = 0; f < NEMB; ++f) s = fmaf(er[f], wr[f], s);
    n1[v * NEMB + tid] = tanhf(3.0f * s);
  } else if (tid >= 64 && tid < 64 + NEMB) {
    const int e = tid - 64;
    float s = b2[e];
    const float* er = emb2 + iv * NEMB;
    const float* wr = W2 + e * NEMB;
    for (int f = 0; f < NEMB; ++f) s = fmaf(er[f], wr[f], s);
    n2[v * NEMB + e] = tanhf(3.0f * s);
  }
}

// ---------------------------------------------------------------- G2: adjacency row + topk + normalize
__global__ __launch_bounds__(256) void g2_kernel(
    const float* __restrict__ n1, const float* __restrict__ n2,
    int* __restrict__ cols, float* __restrict__ wts) {
  const int v = blockIdx.x;
  const int tid = threadIdx.x;
  volatile __shared__ float Arow[NNODE];
  __shared__ float n1v[NEMB], n2v[NEMB];
  if (tid < NEMB) n1v[tid] = n1[v * NEMB + tid];
  if (tid >= 64 && tid < 64 + NEMB) n2v[tid - 64] = n2[v * NEMB + tid - 64];
  __syncthreads();
  for (int w = tid; w < NNODE; w += 256) {
    float d1 = 0.f, d2 = 0.f;
    const float* r1 = n1 + w * NEMB;
    const float* r2 = n2 + w * NEMB;
    for (int e = 0; e < NEMB; ++e) {
      d1 = fmaf(n1v[e], r2[e], d1);
      d2 = fmaf(n2v[e], r1[e], d2);
    }
    float a = tanhf(3.0f * (d1 - d2));
    Arow[w] = a > 0.f ? a : 0.f;
  }
  __syncthreads();
  if (tid >= 64) return;   // single wave does topk; no __syncthreads below
  float sum = 1.0f;        // diagonal of A+I
  float selv[KNEI];
  int seli[KNEI];
  #pragma unroll
  for (int s = 0; s < KNEI; ++s) {
    float bv = -1.f; int bi = NNODE;
    #pragma unroll
    for (int w8 = 0; w8 < NNODE / 64; ++w8) {
      const int w = tid + 64 * w8;
      const float val = Arow[w];
      if (val > bv || (val == bv && w < bi)) { bv = val; bi = w; }
    }
    #pragma unroll
    for (int off = 32; off >= 1; off >>= 1) {
      const float ov = __shfl_down(bv, off);
      const int oi = __shfl_down(bi, off);
      if (ov > bv || (ov == bv && oi < bi)) { bv = ov; bi = oi; }
    }
    bv = __shfl(bv, 0);
    bi = __shfl(bi, 0);
    selv[s] = bv;
    seli[s] = bi;
    Arow[bi] = -2.f;       // mark selected (same value/address from all lanes)
    sum += bv;
  }
  if (tid == 0) {
    const float inv = 1.0f / sum;
    #pragma unroll
    for (int s = 0; s < KNEI; ++s) {
      cols[v * NADJ + s] = seli[s];
      wts[v * NADJ + s] = selv[s] * inv;
    }
    cols[v * NADJ + KNEI] = v;
    wts[v * NADJ + KNEI] = inv;   // diagonal weight 1/sum
  }
}

// ---------------------------------------------------------------- Z: dilated inception gated conv
struct ZParams {
  const float* fw[4]; const float* fb[4];
  const float* gw[4]; const float* gb[4];
};

template <int K>
__device__ __forceinline__ void z_compute(
    const float (*__restrict__ xs)[80], int lane,
    const float* __restrict__ fw, const float* __restrict__ fb,
    const float* __restrict__ gw, const float* __restrict__ gb,
    float* __restrict__ accF, float* __restrict__ accG) {
  const int JS = 7 - K;
  #pragma unroll
  for (int c8 = 0; c8 < 8; ++c8) { accF[c8] = fb[c8]; accG[c8] = gb[c8]; }
  for (int ci = 0; ci < NC; ++ci) {
    float xv[K];
    #pragma unroll
    for (int i = 0; i < K; ++i) xv[i] = xs[ci][lane + 2 * (JS + i)];
    #pragma unroll
    for (int c8 = 0; c8 < 8; ++c8) {
      const float* fwp = fw + (c8 * NC + ci) * K;
      const float* gwp = gw + (c8 * NC + ci) * K;
      #pragma unroll
      for (int i = 0; i < K; ++i) {
        accF[c8] = fmaf(fwp[i], xv[i], accF[c8]);
        accG[c8] = fmaf(gwp[i], xv[i], accG[c8]);
      }
    }
  }
}

__global__ __launch_bounds__(256) void z_kernel(
    const float* __restrict__ x, ZParams p, float* __restrict__ z) {
  __shared__ float xs[NC][80];
  const int tile = blockIdx.x;       // 0..2 -> t0 = 0,64,128
  const int n = blockIdx.y;
  const int b = blockIdx.z;
  const int t0 = tile * 64;
  const int tid = threadIdx.x;
  for (int i = tid; i < NC * 76; i += 256) {
    const int ci = i / 76, tt = i - ci * 76;
    const int tg = t0 + tt;
    xs[ci][tt] = (tg < NT) ? x[((b * NC + ci) * NNODE + n) * NT + tg] : 0.f;
  }
  __syncthreads();
  const int w = tid >> 6, lane = tid & 63;
  const int br = (w + n) & 3;        // rotate branches across waves for SIMD balance
  float accF[8], accG[8];
  switch (br) {
    case 0: z_compute<2>(xs, lane, p.fw[0], p.fb[0], p.gw[0], p.gb[0], accF, accG); break;
    case 1: z_compute<3>(xs, lane, p.fw[1], p.fb[1], p.gw[1], p.gb[1], accF, accG); break;
    case 2: z_compute<6>(xs, lane, p.fw[2], p.fb[2], p.gw[2], p.gb[2], accF, accG); break;
    default: z_compute<7>(xs, lane, p.fw[3], p.fb[3], p.gw[3], p.gb[3], accF, accG); break;
  }
  const int t = t0 + lane;
  if (t < NTO) {
    #pragma unroll
    for (int c8 = 0; c8 < 8; ++c8) {
      const int co = br * 8 + c8;
      const float f = fast_tanh(accF[c8]);
      const float g = fast_sigmoid(accG[c8]);
      z[((b * NC + co) * NNODE + n) * NTO + t] = f * g;
    }
  }
}

// ---------------------------------------------------------------- hop: h = 0.05*z0 + 0.95 * Ah @ zin
__global__ __launch_bounds__(256) void hop_kernel(
    const float* __restrict__ zin, const float* __restrict__ z0,
    const int* __restrict__ cols, const float* __restrict__ wts,
    float* __restrict__ hout) {
  const int i = blockIdx.x * 256 + threadIdx.x;   // (bc, v, q)
  const int q = i % NQ;
  const int r = i / NQ;
  const int v = r % NNODE;
  const int bc = r / NNODE;
  const int rowbase = bc * NNODE;
  const int* cv = cols + v * NADJ;
  const float* wv = wts + v * NADJ;
  float ax = 0.f, ay = 0.f, az = 0.f, aw = 0.f;
  for (int s = 0; s < NADJ; ++s) {
    const int col = cv[s];
    const float wt = wv[s];
    const float4 zv = *reinterpret_cast<const float4*>(zin + (rowbase + col) * NTO + 4 * q);
    ax = fmaf(wt, zv.x, ax); ay = fmaf(wt, zv.y, ay);
    az = fmaf(wt, zv.z, az); aw = fmaf(wt, zv.w, aw);
  }
  const float4 zz = *reinterpret_cast<const float4*>(z0 + (rowbase + v) * NTO + 4 * q);
  float4 o;
  o.x = fmaf(0.95f, ax, 0.05f * zz.x);
  o.y = fmaf(0.95f, ay, 0.05f * zz.y);
  o.z = fmaf(0.95f, az, 0.05f * zz.z);
  o.w = fmaf(0.95f, aw, 0.05f * zz.w);
  *reinterpret_cast<float4*>(hout + (rowbase + v) * NTO + 4 * q) = o;
}

// ---------------------------------------------------------------- M: 1x1 mlp + residual + batch stats
__global__ __launch_bounds__(256) void mlp_kernel(
    const float* __restrict__ z, const float* __restrict__ h1,
    const float* __restrict__ h2, const float* __restrict__ x,
    const float* __restrict__ mw, const float* __restrict__ mb,
    float* __restrict__ out, float* __restrict__ stats) {
  const int i = blockIdx.x * 256 + threadIdx.x;   // (b, v, q) : 32*512*39
  const int q = i % NQ;
  const int r = i / NQ;
  const int v = r % NNODE;
  const int b = r / NNODE;
  float4 acc[NC];
  #pragma unroll
  for (int co = 0; co < NC; ++co) {
    const float bb = mb[co];
    acc[co].x = bb; acc[co].y = bb; acc[co].z = bb; acc[co].w = bb;
  }
  for (int c = 0; c < NC; ++c) {
    const int base = ((b * NC + c) * NNODE + v) * NTO + 4 * q;
    const float4 zc = *reinterpret_cast<const float4*>(z + base);
    const float4 h1c = *reinterpret_cast<const float4*>(h1 + base);
    const float4 h2c = *reinterpret_cast<const float4*>(h2 + base);
    #pragma unroll
    for (int co = 0; co < NC; ++co) {
      const float m0 = mw[co * 96 + c];
      const float m1 = mw[co * 96 + 32 + c];
      const float m2 = mw[co * 96 + 64 + c];
      acc[co].x = fmaf(m0, zc.x, acc[co].x); acc[co].y = fmaf(m0, zc.y, acc[co].y);
      acc[co].z = fmaf(m0, zc.z, acc[co].z); acc[co].w = fmaf(m0, zc.w, acc[co].w);
      acc[co].x = fmaf(m1, h1c.x, acc[co].x); acc[co].y = fmaf(m1, h1c.y, acc[co].y);
      acc[co].z = fmaf(m1, h1c.z, acc[co].z); acc[co].w = fmaf(m1, h1c.w, acc[co].w);
      acc[co].x = fmaf(m2, h2c.x, acc[co].x); acc[co].y = fmaf(m2, h2c.y, acc[co].y);
      acc[co].z = fmaf(m2, h2c.z, acc[co].z); acc[co].w = fmaf(m2, h2c.w, acc[co].w);
    }
  }
  float s1 = 0.f, s2 = 0.f;
  #pragma unroll
  for (int co = 0; co < NC; ++co) {
    const int xb = ((b * NC + co) * NNODE + v) * NT + 12 + 4 * q;
    const float4 xr = *reinterpret_cast<const float4*>(x + xb);
    float4 o;
    o.x = acc[co].x + xr.x; o.y = acc[co].y + xr.y;
    o.z = acc[co].z + xr.z; o.w = acc[co].w + xr.w;
    const int ob = ((b * NC + co) * NNODE + v) * NTO + 4 * q;
    *reinterpret_cast<float4*>(out + ob) = o;
    s1 += o.x + o.y + o.z + o.w;
    s2 += o.x * o.x + o.y * o.y + o.z * o.z + o.w * o.w;
  }
  #pragma unroll
  for (int off = 32; off >= 1; off >>= 1) {
    s1 += __shfl_down(s1, off);
    s2 += __shfl_down(s2, off);
  }
  __shared__ float r1[4], r2[4];
  const int lane = threadIdx.x & 63, wv_ = threadIdx.x >> 6;
  if (lane == 0) { r1[wv_] = s1; r2[wv_] = s2; }
  __syncthreads();
  if (threadIdx.x == 0) {   // b is uniform per block (19968 threads per b = 78 blocks)
    atomicAdd(&stats[b * 2], r1[0] + r1[1] + r1[2] + r1[3]);
    atomicAdd(&stats[b * 2 + 1], r2[0] + r2[1] + r2[2] + r2[3]);
  }
}

// ---------------------------------------------------------------- L: layernorm (in-place on out)
__global__ __launch_bounds__(256) void ln_kernel(
    float* __restrict__ out, const float* __restrict__ lnw,
    const float* __restrict__ lnb, const int* __restrict__ idx,
    const float* __restrict__ stats) {
  const int i = blockIdx.x * 256 + threadIdx.x;   // quads over (b,co,v,q)
  const int q = i % NQ;
  const int r = i / NQ;
  const int v = r % NNODE;
  const int r2 = r / NNODE;
  const int co = r2 % NC;
  const int b = r2 / NC;
  const float invM = 1.0f / (float)(NC * NNODE * NTO);
  const float mean = stats[b * 2] * invM;
  const float var = stats[b * 2 + 1] * invM - mean * mean;
  const float rs = rsqrtf(var + 1e-5f);
  float4 o = *reinterpret_cast<const float4*>(out + 4 * i);
  const int iv = idx[v];
  const int lb = (co * NNODE + iv) * NTO + 4 * q;
  const float4 w = *reinterpret_cast<const float4*>(lnw + lb);
  const float4 bb = *reinterpret_cast<const float4*>(lnb + lb);
  o.x = (o.x - mean) * rs * w.x + bb.x;
  o.y = (o.y - mean) * rs * w.y + bb.y;
  o.z = (o.z - mean) * rs * w.z + bb.z;
  o.w = (o.w - mean) * rs * w.w + bb.w;
  *reinterpret_cast<float4*>(out + 4 * i) = o;
}

// ---------------------------------------------------------------- launch
extern "C" void kernel_launch(void* const* d_in, const int* in_sizes, int n_in,
                              void* d_out, int out_size, void* d_ws, size_t ws_size,
                              hipStream_t stream) {
  const float* x    = (const float*)d_in[0];
  const int*   idx  = (const int*)d_in[1];
  const float* emb1 = (const float*)d_in[2];
  const float* emb2 = (const float*)d_in[3];
  const float* W1   = (const float*)d_in[4];
  const float* b1   = (const float*)d_in[5];
  const float* W2   = (const float*)d_in[6];
  const float* b2   = (const float*)d_in[7];
  const float* mlp_w = (const float*)d_in[24];
  const float* mlp_b = (const float*)d_in[25];
  const float* ln_w = (const float*)d_in[26];
  const float* ln_b = (const float*)d_in[27];

  char* ws = (char*)d_ws;
  float* n1    = (float*)(ws);
  float* n2    = (float*)(ws + (128 << 10));
  int*   cols  = (int*)  (ws + (256 << 10));
  float* wts   = (float*)(ws + (320 << 10));
  float* stats = (float*)(ws + (384 << 10));
  const size_t zbytes = (size_t)NB * NC * NNODE * NTO * 4;
  float* z  = (float*)(ws + (512 << 10));
  float* h1 = (float*)(ws + (512 << 10) + zbytes);
  float* h2 = (float*)(ws + (512 << 10) + 2 * zbytes);

  ZParams zp;
  for (int k = 0; k < 4; ++k) {
    zp.fw[k] = (const float*)d_in[8 + 2 * k];
    zp.fb[k] = (const float*)d_in[9 + 2 * k];
    zp.gw[k] = (const float*)d_in[16 + 2 * k];
    zp.gb[k] = (const float*)d_in[17 + 2 * k];
  }

  hipMemsetAsync(stats, 0, 2 * NB * sizeof(float), stream);
  g1_kernel<<<NNODE, 128, 0, stream>>>(emb1, emb2, W1, b1, W2, b2, idx, n1, n2);
  g2_kernel<<<NNODE, 256, 0, stream>>>(n1, n2, cols, wts);
  z_kernel<<<dim3(3, NNODE, NB), 256, 0, stream>>>(x, zp, z);
  const int hopBlocks = NB * NC * NNODE * NQ / 256;   // 79872
  hop_kernel<<<hopBlocks, 256, 0, stream>>>(z, z, cols, wts, h1);
  hop_kernel<<<hopBlocks, 256, 0, stream>>>(h1, z, cols, wts, h2);
  mlp_kernel<<<NB * NNODE * NQ / 256, 256, 0, stream>>>(z, h1, h2, x, mlp_w, mlp_b,
                                                        (float*)d_out, stats);
  ln_kernel<<<NB * NC * NNODE * NQ / 256, 256, 0, stream>>>((float*)d_out, ln_w, ln_b,
                                                            idx, stats);
}

// Round 2
// 1885.066 us; speedup vs baseline: 1.4883x; 1.4883x over previous
//
#include <hip/hip_runtime.h>

#define NB 32
#define NC 32
#define NNODE 512
#define NT 168
#define NTO 156
#define NQ 39          // NTO / 4
#define NEMB 40
#define KNEI 20
#define NADJ 21        // 20 neighbors + diagonal

static_assert(NTO == 4 * NQ, "t quads");

typedef __attribute__((ext_vector_type(8))) short bf16x8;
typedef __attribute__((ext_vector_type(16))) float f32x16;

// ---------------------------------------------------------------- helpers
__device__ __forceinline__ float fast_tanh(float x) {
  float e = __expf(2.0f * x);
  return 1.0f - 2.0f / (e + 1.0f);
}
__device__ __forceinline__ float fast_sigmoid(float x) {
  return 1.0f / (1.0f + __expf(-x));
}
__device__ __forceinline__ unsigned short f2b(float v) {   // f32 -> bf16 RNE
  unsigned int u = __float_as_uint(v);
  unsigned int r = (u + 0x7FFFu + ((u >> 16) & 1u)) >> 16;
  return (unsigned short)r;
}

// ---------------------------------------------------------------- G1: node embeddings
__global__ __launch_bounds__(128) void g1_kernel(
    const float* __restrict__ emb1, const float* __restrict__ emb2,
    const float* __restrict__ W1, const float* __restrict__ b1,
    const float* __restrict__ W2, const float* __restrict__ b2,
    const int* __restrict__ idx, float* __restrict__ n1, float* __restrict__ n2) {
  const int v = blockIdx.x;
  const int tid = threadIdx.x;
  const int iv = idx[v];
  if (tid < NEMB) {
    float s = b1[tid];
    const float* er = emb1 + iv * NEMB;
    const float* wr = W1 + tid * NEMB;
    for (int f = 0; f < NEMB; ++f) s = fmaf(er[f], wr[f], s);
    n1[v * NEMB + tid] = tanhf(3.0f * s);
  } else if (tid >= 64 && tid < 64 + NEMB) {
    const int e = tid - 64;
    float s = b2[e];
    const float* er = emb2 + iv * NEMB;
    const float* wr = W2 + e * NEMB;
    for (int f = 0; f < NEMB; ++f) s = fmaf(er[f], wr[f], s);
    n2[v * NEMB + e] = tanhf(3.0f * s);
  }
}

// ---------------------------------------------------------------- G2: adjacency row + topk + normalize
__global__ __launch_bounds__(256) void g2_kernel(
    const float* __restrict__ n1, const float* __restrict__ n2,
    int* __restrict__ cols, float* __restrict__ wts) {
  const int v = blockIdx.x;
  const int tid = threadIdx.x;
  volatile __shared__ float Arow[NNODE];
  __shared__ float n1v[NEMB], n2v[NEMB];
  if (tid < NEMB) n1v[tid] = n1[v * NEMB + tid];
  if (tid >= 64 && tid < 64 + NEMB) n2v[tid - 64] = n2[v * NEMB + tid - 64];
  __syncthreads();
  for (int w = tid; w < NNODE; w += 256) {
    float d1 = 0.f, d2 = 0.f;
    const float* r1 = n1 + w * NEMB;
    const float* r2 = n2 + w * NEMB;
    for (int e = 0; e < NEMB; ++e) {
      d1 = fmaf(n1v[e], r2[e], d1);
      d2 = fmaf(n2v[e], r1[e], d2);
    }
    float a = tanhf(3.0f * (d1 - d2));
    Arow[w] = a > 0.f ? a : 0.f;
  }
  __syncthreads();
  if (tid >= 64) return;   // single wave does topk
  float sum = 1.0f;        // diagonal of A+I
  float selv[KNEI];
  int seli[KNEI];
  #pragma unroll
  for (int s = 0; s < KNEI; ++s) {
    float bv = -1.f; int bi = NNODE;
    #pragma unroll
    for (int w8 = 0; w8 < NNODE / 64; ++w8) {
      const int w = tid + 64 * w8;
      const float val = Arow[w];
      if (val > bv || (val == bv && w < bi)) { bv = val; bi = w; }
    }
    #pragma unroll
    for (int off = 32; off >= 1; off >>= 1) {
      const float ov = __shfl_down(bv, off);
      const int oi = __shfl_down(bi, off);
      if (ov > bv || (ov == bv && oi < bi)) { bv = ov; bi = oi; }
    }
    bv = __shfl(bv, 0);
    bi = __shfl(bi, 0);
    selv[s] = bv;
    seli[s] = bi;
    Arow[bi] = -2.f;
    sum += bv;
  }
  if (tid == 0) {
    const float inv = 1.0f / sum;
    #pragma unroll
    for (int s = 0; s < KNEI; ++s) {
      cols[v * NADJ + s] = seli[s];
      wts[v * NADJ + s] = selv[s] * inv;
    }
    cols[v * NADJ + KNEI] = v;
    wts[v * NADJ + KNEI] = inv;
  }
}

// ---------------------------------------------------------------- weights struct
struct ZParams {
  const float* fw[4]; const float* fb[4];
  const float* gw[4]; const float* gb[4];
};

// ---------------------------------------------------------------- pack A-fragments + bias for MFMA
// packedA layout: [m(2)][s(2)][j(7)][lane(64)][e(8)] bf16 (ushort)
//   A-frag for mfma_f32_32x32x16_bf16: lane l holds A[row=l&31][k=(l>>5)*8+e]
//   M-tile m: rows 0..15 = filt co m*16+row, rows 16..31 = gate co m*16+row-16
//   K-step s: ci = s*16 + k
// packedBias: [m(2)][lane(64)][r(16)] f32, D-layout row=(r&3)+8*(r>>2)+4*(l>>5);
//   r<8 -> filt bias of co, r>=8 -> gate bias
__global__ __launch_bounds__(256) void pack_kernel(ZParams p, unsigned short* __restrict__ pA,
                                                   float* __restrict__ pB) {
  const int idx = blockIdx.x * 256 + threadIdx.x;
  if (idx < 2 * 2 * 7 * 64 * 8) {
    const int e = idx & 7;
    const int l = (idx >> 3) & 63;
    int rest = idx >> 9;
    const int j = rest % 7;
    rest /= 7;
    const int s = rest & 1;
    const int m = rest >> 1;
    const int row = l & 31;
    const int k = ((l >> 5) << 3) + e;
    const int ci = s * 16 + k;
    int co; const float* arr4[4]; int isF = (row < 16);
    co = m * 16 + (isF ? row : row - 16);
    const int br = co >> 3;
    const int kk = (br == 0) ? 2 : (br == 1) ? 3 : (br == 2) ? 6 : 7;
    const int jw = j - (7 - kk);
    const float* arr = isF ? p.fw[br] : p.gw[br];
    float val = (jw >= 0) ? arr[((co & 7) * NC + ci) * kk + jw] : 0.f;
    pA[idx] = f2b(val);
  } else if (idx < 2 * 2 * 7 * 64 * 8 + 2 * 64 * 16) {
    const int ib = idx - 2 * 2 * 7 * 64 * 8;
    const int r = ib & 15;
    const int l = (ib >> 4) & 63;
    const int m = ib >> 10;
    const int rr = r & 7;
    const int row = (rr & 3) + 8 * (rr >> 2) + 4 * (l >> 5);
    const int co = m * 16 + row;
    const int br = co >> 3;
    const float* arr = (r < 8) ? p.fb[br] : p.gb[br];
    pB[ib] = arr[co & 7];
  }
}

// ---------------------------------------------------------------- Z: MFMA gated inception conv
// block = (n, b); 4 waves: wave w -> M-tile m=w&1, N-tiles {0,1,2} or {3,4} (t0=32*nt)
// LDS: x transposed bf16, xt[t(176)][ci(40 pitch)]
#define XT_PITCH 40
__global__ __launch_bounds__(256) void zmfma_kernel(
    const float* __restrict__ x, const unsigned short* __restrict__ pA,
    const float* __restrict__ pBias, float* __restrict__ z) {
  __shared__ unsigned short xt[176 * XT_PITCH];
  const int n = blockIdx.x;
  const int b = blockIdx.y;
  const int tid = threadIdx.x;
  // stage x -> LDS (bf16, transposed), zero-pad t >= 168
  for (int i = tid; i < NC * 176; i += 256) {
    const int ci = i / 176;
    const int t = i - ci * 176;
    float v = (t < NT) ? x[((b * NC + ci) * NNODE + n) * NT + t] : 0.f;
    xt[t * XT_PITCH + ci] = f2b(v);
  }
  __syncthreads();
  const int w = tid >> 6, l = tid & 63;
  const int jc = l & 31, h = l >> 5;
  const int m = w & 1;
  const int ntBase = (w >> 1) ? 3 : 0;
  const int ntCount = (w >> 1) ? 2 : 3;
  // load A fragments (coalesced, L2-resident)
  bf16x8 aF[2][7];
  #pragma unroll
  for (int s = 0; s < 2; ++s)
    #pragma unroll
    for (int j = 0; j < 7; ++j)
      aF[s][j] = *reinterpret_cast<const bf16x8*>(
          pA + ((((m * 2 + s) * 7 + j) << 6) + l) * 8);
  // bias in D layout
  f32x16 accBias;
  const float* pb = pBias + (m * 64 + l) * 16;
  #pragma unroll
  for (int r = 0; r < 16; ++r) accBias[r] = pb[r];

  for (int nt = 0; nt < ntCount; ++nt) {
    const int t0 = (ntBase + nt) * 32;
    f32x16 acc = accBias;
    #pragma unroll
    for (int j = 0; j < 7; ++j) {
      const int row = t0 + jc + 2 * j;
      const unsigned short* bp = &xt[row * XT_PITCH + h * 8];
      bf16x8 b0 = *reinterpret_cast<const bf16x8*>(bp);        // ci 0..15
      bf16x8 b1 = *reinterpret_cast<const bf16x8*>(bp + 16);   // ci 16..31
      acc = __builtin_amdgcn_mfma_f32_32x32x16_bf16(aF[0][j], b0, acc, 0, 0, 0);
      acc = __builtin_amdgcn_mfma_f32_32x32x16_bf16(aF[1][j], b1, acc, 0, 0, 0);
    }
    const int t = t0 + jc;
    if (t < NTO) {
      #pragma unroll
      for (int r = 0; r < 8; ++r) {
        const float f = fast_tanh(acc[r]);
        const float g = fast_sigmoid(acc[r + 8]);
        const int row = (r & 3) + 8 * (r >> 2) + 4 * h;   // 0..15
        const int co = m * 16 + row;
        z[((b * NC + co) * NNODE + n) * NTO + t] = f * g;
      }
    }
  }
}

// ---------------------------------------------------------------- hop: h = 0.05*z0 + 0.95 * Ah @ zin
__global__ __launch_bounds__(256) void hop_kernel(
    const float* __restrict__ zin, const float* __restrict__ z0,
    const int* __restrict__ cols, const float* __restrict__ wts,
    float* __restrict__ hout) {
  const int i = blockIdx.x * 256 + threadIdx.x;   // (bc, v, q)
  const int q = i % NQ;
  const int r = i / NQ;
  const int v = r % NNODE;
  const int bc = r / NNODE;
  const int rowbase = bc * NNODE;
  const int* cv = cols + v * NADJ;
  const float* wv = wts + v * NADJ;
  float ax = 0.f, ay = 0.f, az = 0.f, aw = 0.f;
  for (int s = 0; s < NADJ; ++s) {
    const int col = cv[s];
    const float wt = wv[s];
    const float4 zv = *reinterpret_cast<const float4*>(zin + (rowbase + col) * NTO + 4 * q);
    ax = fmaf(wt, zv.x, ax); ay = fmaf(wt, zv.y, ay);
    az = fmaf(wt, zv.z, az); aw = fmaf(wt, zv.w, aw);
  }
  const float4 zz = *reinterpret_cast<const float4*>(z0 + (rowbase + v) * NTO + 4 * q);
  float4 o;
  o.x = fmaf(0.95f, ax, 0.05f * zz.x);
  o.y = fmaf(0.95f, ay, 0.05f * zz.y);
  o.z = fmaf(0.95f, az, 0.05f * zz.z);
  o.w = fmaf(0.95f, aw, 0.05f * zz.w);
  *reinterpret_cast<float4*>(hout + (rowbase + v) * NTO + 4 * q) = o;
}

// ---------------------------------------------------------------- M: 1x1 mlp + residual + batch stats
__global__ __launch_bounds__(256) void mlp_kernel(
    const float* __restrict__ z, const float* __restrict__ h1,
    const float* __restrict__ h2, const float* __restrict__ x,
    const float* __restrict__ mw, const float* __restrict__ mb,
    float* __restrict__ out, float* __restrict__ stats) {
  const int i = blockIdx.x * 256 + threadIdx.x;   // (b, v, q)
  const int q = i % NQ;
  const int r = i / NQ;
  const int v = r % NNODE;
  const int b = r / NNODE;
  float4 acc[NC];
  #pragma unroll
  for (int co = 0; co < NC; ++co) {
    const float bb = mb[co];
    acc[co].x = bb; acc[co].y = bb; acc[co].z = bb; acc[co].w = bb;
  }
  for (int c = 0; c < NC; ++c) {
    const int base = ((b * NC + c) * NNODE + v) * NTO + 4 * q;
    const float4 zc = *reinterpret_cast<const float4*>(z + base);
    const float4 h1c = *reinterpret_cast<const float4*>(h1 + base);
    const float4 h2c = *reinterpret_cast<const float4*>(h2 + base);
    #pragma unroll
    for (int co = 0; co < NC; ++co) {
      const float m0 = mw[co * 96 + c];
      const float m1 = mw[co * 96 + 32 + c];
      const float m2 = mw[co * 96 + 64 + c];
      acc[co].x = fmaf(m0, zc.x, acc[co].x); acc[co].y = fmaf(m0, zc.y, acc[co].y);
      acc[co].z = fmaf(m0, zc.z, acc[co].z); acc[co].w = fmaf(m0, zc.w, acc[co].w);
      acc[co].x = fmaf(m1, h1c.x, acc[co].x); acc[co].y = fmaf(m1, h1c.y, acc[co].y);
      acc[co].z = fmaf(m1, h1c.z, acc[co].z); acc[co].w = fmaf(m1, h1c.w, acc[co].w);
      acc[co].x = fmaf(m2, h2c.x, acc[co].x); acc[co].y = fmaf(m2, h2c.y, acc[co].y);
      acc[co].z = fmaf(m2, h2c.z, acc[co].z); acc[co].w = fmaf(m2, h2c.w, acc[co].w);
    }
  }
  float s1 = 0.f, s2 = 0.f;
  #pragma unroll
  for (int co = 0; co < NC; ++co) {
    const int xb = ((b * NC + co) * NNODE + v) * NT + 12 + 4 * q;
    const float4 xr = *reinterpret_cast<const float4*>(x + xb);
    float4 o;
    o.x = acc[co].x + xr.x; o.y = acc[co].y + xr.y;
    o.z = acc[co].z + xr.z; o.w = acc[co].w + xr.w;
    const int ob = ((b * NC + co) * NNODE + v) * NTO + 4 * q;
    *reinterpret_cast<float4*>(out + ob) = o;
    s1 += o.x + o.y + o.z + o.w;
    s2 += o.x * o.x + o.y * o.y + o.z * o.z + o.w * o.w;
  }
  #pragma unroll
  for (int off = 32; off >= 1; off >>= 1) {
    s1 += __shfl_down(s1, off);
    s2 += __shfl_down(s2, off);
  }
  __shared__ float r1[4], r2[4];
  const int lane = threadIdx.x & 63, wv_ = threadIdx.x >> 6;
  if (lane == 0) { r1[wv_] = s1; r2[wv_] = s2; }
  __syncthreads();
  if (threadIdx.x == 0) {
    atomicAdd(&stats[b * 2], r1[0] + r1[1] + r1[2] + r1[3]);
    atomicAdd(&stats[b * 2 + 1], r2[0] + r2[1] + r2[2] + r2[3]);
  }
}

// ---------------------------------------------------------------- L: layernorm (in-place on out)
__global__ __launch_bounds__(256) void ln_kernel(
    float* __restrict__ out, const float* __restrict__ lnw,
    const float* __restrict__ lnb, const int* __restrict__ idx,
    const float* __restrict__ stats) {
  const int i = blockIdx.x * 256 + threadIdx.x;
  const int q = i % NQ;
  const int r = i / NQ;
  const int v = r % NNODE;
  const int r2 = r / NNODE;
  const int co = r2 % NC;
  const float invM = 1.0f / (float)(NC * NNODE * NTO);
  const int b = r2 / NC;
  const float mean = stats[b * 2] * invM;
  const float var = stats[b * 2 + 1] * invM - mean * mean;
  const float rs = rsqrtf(var + 1e-5f);
  float4 o = *reinterpret_cast<const float4*>(out + 4 * i);
  const int iv = idx[v];
  const int lb = (co * NNODE + iv) * NTO + 4 * q;
  const float4 w = *reinterpret_cast<const float4*>(lnw + lb);
  const float4 bb = *reinterpret_cast<const float4*>(lnb + lb);
  o.x = (o.x - mean) * rs * w.x + bb.x;
  o.y = (o.y - mean) * rs * w.y + bb.y;
  o.z = (o.z - mean) * rs * w.z + bb.z;
  o.w = (o.w - mean) * rs * w.w + bb.w;
  *reinterpret_cast<float4*>(out + 4 * i) = o;
}

// ---------------------------------------------------------------- launch
extern "C" void kernel_launch(void* const* d_in, const int* in_sizes, int n_in,
                              void* d_out, int out_size, void* d_ws, size_t ws_size,
                              hipStream_t stream) {
  const float* x    = (const float*)d_in[0];
  const int*   idx  = (const int*)d_in[1];
  const float* emb1 = (const float*)d_in[2];
  const float* emb2 = (const float*)d_in[3];
  const float* W1   = (const float*)d_in[4];
  const float* b1   = (const float*)d_in[5];
  const float* W2   = (const float*)d_in[6];
  const float* b2   = (const float*)d_in[7];
  const float* mlp_w = (const float*)d_in[24];
  const float* mlp_b = (const float*)d_in[25];
  const float* ln_w = (const float*)d_in[26];
  const float* ln_b = (const float*)d_in[27];

  char* ws = (char*)d_ws;
  float* n1    = (float*)(ws);
  float* n2    = (float*)(ws + (128 << 10));
  int*   cols  = (int*)  (ws + (256 << 10));
  float* wts   = (float*)(ws + (320 << 10));
  float* stats = (float*)(ws + (384 << 10));
  unsigned short* pA = (unsigned short*)(ws + (400 << 10));   // 28,672 B
  float* pBias = (float*)(ws + (440 << 10));                  // 8,192 B
  const size_t zbytes = (size_t)NB * NC * NNODE * NTO * 4;
  float* z  = (float*)(ws + (512 << 10));
  float* h1 = (float*)(ws + (512 << 10) + zbytes);
  float* h2 = (float*)(ws + (512 << 10) + 2 * zbytes);

  ZParams zp;
  for (int k = 0; k < 4; ++k) {
    zp.fw[k] = (const float*)d_in[8 + 2 * k];
    zp.fb[k] = (const float*)d_in[9 + 2 * k];
    zp.gw[k] = (const float*)d_in[16 + 2 * k];
    zp.gb[k] = (const float*)d_in[17 + 2 * k];
  }

  hipMemsetAsync(stats, 0, 2 * NB * sizeof(float), stream);
  g1_kernel<<<NNODE, 128, 0, stream>>>(emb1, emb2, W1, b1, W2, b2, idx, n1, n2);
  g2_kernel<<<NNODE, 256, 0, stream>>>(n1, n2, cols, wts);
  pack_kernel<<<64, 256, 0, stream>>>(zp, pA, pBias);
  zmfma_kernel<<<dim3(NNODE, NB), 256, 0, stream>>>(x, pA, pBias, z);
  const int hopBlocks = NB * NC * NNODE * NQ / 256;   // 79872
  hop_kernel<<<hopBlocks, 256, 0, stream>>>(z, z, cols, wts, h1);
  hop_kernel<<<hopBlocks, 256, 0, stream>>>(h1, z, cols, wts, h2);
  mlp_kernel<<<NB * NNODE * NQ / 256, 256, 0, stream>>>(z, h1, h2, x, mlp_w, mlp_b,
                                                        (float*)d_out, stats);
  ln_kernel<<<NB * NC * NNODE * NQ / 256, 256, 0, stream>>>((float*)d_out, ln_w, ln_b,
                                                            idx, stats);
}